// Round 1
// baseline (549.109 us; speedup 1.0000x reference)
//
#include <hip/hip_runtime.h>
#include <stdint.h>

#define E_ 8
#define M_ 8192
#define K_ 2048
#define N_ 8192

#define BM 128
#define BN 128
#define BK 32

typedef __attribute__((ext_vector_type(8))) short bf16x8;
typedef __attribute__((ext_vector_type(4))) float f32x4;
typedef __attribute__((ext_vector_type(8))) unsigned short us8;

__device__ __forceinline__ unsigned short f2bf(float f) {
  union { float f; uint32_t u; } v; v.f = f;
  uint32_t u = v.u;
  uint32_t r = (u + 0x7FFFu + ((u >> 16) & 1u)) >> 16;
  return (unsigned short)r;
}

__device__ __forceinline__ void gload_lds16(const void* g, void* l) {
  __builtin_amdgcn_global_load_lds(
      (const __attribute__((address_space(1))) unsigned int*)g,
      (__attribute__((address_space(3))) unsigned int*)l,
      16, 0, 0);
}

// ---------------- fp32 -> bf16, layout preserving (inputs) ----------------
__global__ __launch_bounds__(256) void conv_a(const float* __restrict__ A,
                                              unsigned short* __restrict__ Ab,
                                              int n8) {
  int stride = gridDim.x * blockDim.x;
  for (int idx = blockIdx.x * blockDim.x + threadIdx.x; idx < n8; idx += stride) {
    const float4* p = reinterpret_cast<const float4*>(A) + (size_t)idx * 2;
    float4 x0 = p[0], x1 = p[1];
    us8 o;
    o[0] = f2bf(x0.x); o[1] = f2bf(x0.y); o[2] = f2bf(x0.z); o[3] = f2bf(x0.w);
    o[4] = f2bf(x1.x); o[5] = f2bf(x1.y); o[6] = f2bf(x1.z); o[7] = f2bf(x1.w);
    *reinterpret_cast<us8*>(Ab + (size_t)idx * 8) = o;
  }
}

// ------------- fp32 W[e][K][N] -> bf16 Wt[e][N][K] (transpose) -------------
__global__ __launch_bounds__(256) void conv_wT(const float* __restrict__ W,
                                               unsigned short* __restrict__ Wt,
                                               int e_fixed) {
  __shared__ float t[64][65];
  int tid = threadIdx.x;
  int tx = tid & 63, ty = tid >> 6;
  int n0 = blockIdx.x * 64, k0 = blockIdx.y * 64;
  int e = (gridDim.z > 1) ? blockIdx.z : e_fixed;
  size_t win = (size_t)e * K_ * N_;
  size_t wout = (gridDim.z > 1) ? win : 0;

  #pragma unroll
  for (int r = 0; r < 16; ++r) {
    int kl = r * 4 + ty;
    t[kl][tx] = W[win + (size_t)(k0 + kl) * N_ + n0 + tx];
  }
  __syncthreads();
  #pragma unroll
  for (int r = 0; r < 16; ++r) {
    int nl = r * 4 + ty;
    Wt[wout + (size_t)(n0 + nl) * K_ + k0 + tx] = f2bf(t[tx][nl]);
  }
}

// ---------------- grouped bf16 GEMM, m97 structure ----------------
__global__ __launch_bounds__(256) void moe_gemm_bf16(
    const unsigned short* __restrict__ Ab,   // [M][K] bf16
    const unsigned short* __restrict__ Wt,   // [e][N][K] bf16 (or single expert)
    const int* __restrict__ gs,
    const float* __restrict__ bias,
    float* __restrict__ C,
    int only_expert, size_t wt_stride) {
  __shared__ unsigned short lsA[BM * BK];
  __shared__ unsigned short lsB[BN * BK];

  int tile_n = blockIdx.x;
  int tile_m = blockIdx.y;

  // map row-tile -> (expert, row_start, rows); wave-uniform scalar scan
  int expert = -1, row_start = 0, rows = 0;
  if (only_expert >= 0) {
    int off = 0;
    for (int e = 0; e < only_expert; ++e) off += gs[e];
    int g = gs[only_expert];
    int t0 = tile_m * BM;
    if (t0 >= g) return;
    expert = only_expert;
    row_start = off + t0;
    rows = min(BM, g - t0);
  } else {
    int acc = 0, off = 0;
    for (int e = 0; e < E_; ++e) {
      int g = gs[e];
      int t = (g + BM - 1) / BM;
      if (expert < 0 && tile_m < acc + t) {
        int lt = tile_m - acc;
        expert = e;
        row_start = off + lt * BM;
        rows = min(BM, g - lt * BM);
      }
      acc += t;
      off += g;
    }
    if (expert < 0) return;
  }

  const unsigned short* WtE = Wt + (size_t)expert * wt_stride;

  int tid = threadIdx.x;
  int lane = tid & 63;
  int wave = tid >> 6;
  int wr = wave >> 1, wc = wave & 1;
  int n0 = tile_n * BN;

  f32x4 acc4[4][4];
  #pragma unroll
  for (int i = 0; i < 4; ++i)
    #pragma unroll
    for (int j = 0; j < 4; ++j)
      acc4[i][j] = f32x4{0.f, 0.f, 0.f, 0.f};

  int srow = wave * 16 + (lane >> 2);  // staging row within 64-row half
  int schunk = (lane & 3) * 8;         // staging k-chunk (bf16 elems)

  for (int kk = 0; kk < K_; kk += BK) {
    __syncthreads();  // previous iteration's LDS reads complete
    #pragma unroll
    for (int h = 0; h < 2; ++h) {
      int r = h * 64 + srow;  // 0..127
      int gr = (r < rows) ? (row_start + r) : row_start;  // clamp padded rows
      gload_lds16(Ab + (size_t)gr * K_ + kk + schunk,
                  &lsA[(h * 64 + wave * 16) * BK]);
      gload_lds16(WtE + (size_t)(n0 + r) * K_ + kk + schunk,
                  &lsB[(h * 64 + wave * 16) * BK]);
    }
    __syncthreads();  // compiler drains vmcnt before s_barrier

    bf16x8 afr[4], bfr[4];
    #pragma unroll
    for (int i = 0; i < 4; ++i)
      afr[i] = *reinterpret_cast<const bf16x8*>(
          &lsA[(wr * 64 + i * 16 + (lane & 15)) * BK + (lane >> 4) * 8]);
    #pragma unroll
    for (int j = 0; j < 4; ++j)
      bfr[j] = *reinterpret_cast<const bf16x8*>(
          &lsB[(wc * 64 + j * 16 + (lane & 15)) * BK + (lane >> 4) * 8]);
    #pragma unroll
    for (int i = 0; i < 4; ++i)
      #pragma unroll
      for (int j = 0; j < 4; ++j)
        acc4[i][j] =
            __builtin_amdgcn_mfma_f32_16x16x32_bf16(afr[i], bfr[j], acc4[i][j], 0, 0, 0);
  }

  // epilogue: C = acc + bias ; C/D layout col=lane&15, row=(lane>>4)*4+reg
  float bv[4];
  #pragma unroll
  for (int j = 0; j < 4; ++j) bv[j] = bias[n0 + wc * 64 + j * 16 + (lane & 15)];
  #pragma unroll
  for (int i = 0; i < 4; ++i) {
    int rl0 = wr * 64 + i * 16 + (lane >> 4) * 4;
    #pragma unroll
    for (int r = 0; r < 4; ++r) {
      int lr = rl0 + r;
      if (lr < rows) {
        float* Cp = C + (size_t)(row_start + lr) * N_ + n0 + wc * 64 + (lane & 15);
        #pragma unroll
        for (int j = 0; j < 4; ++j) Cp[j * 16] = acc4[i][j][r] + bv[j];
      }
    }
  }
}

// ---------------- naive fp32 fallback (only if workspace too small) ----------------
__global__ __launch_bounds__(256) void moe_naive(const float* __restrict__ A,
                                                 const float* __restrict__ W,
                                                 const int* __restrict__ gs,
                                                 const float* __restrict__ bias,
                                                 float* __restrict__ C) {
  int col = blockIdx.x * 16 + (threadIdx.x & 15);
  int row = blockIdx.y * 16 + (threadIdx.x >> 4);
  int acc = 0, e = E_ - 1;
  for (int i = 0; i < E_; ++i) {
    int g = gs[i];
    if (row >= acc && row < acc + g) { e = i; break; }
    acc += g;
  }
  const float* a = A + (size_t)row * K_;
  const float* w = W + (size_t)e * K_ * N_ + col;
  float s = 0.f;
  for (int k = 0; k < K_; ++k) s += a[k] * w[(size_t)k * N_];
  C[(size_t)row * N_ + col] = s + bias[col];
}

extern "C" void kernel_launch(void* const* d_in, const int* in_sizes, int n_in,
                              void* d_out, int out_size, void* d_ws, size_t ws_size,
                              hipStream_t stream) {
  const float* A = (const float*)d_in[0];
  const float* W = (const float*)d_in[1];
  const int* gs = (const int*)d_in[2];
  const float* bias = (const float*)d_in[3];
  float* C = (float*)d_out;

  const size_t needA = (size_t)M_ * K_ * 2;        // 32 MiB
  const size_t needWall = (size_t)E_ * K_ * N_ * 2;  // 256 MiB
  const size_t needW1 = (size_t)K_ * N_ * 2;       // 32 MiB

  if (ws_size >= needA + needWall) {
    unsigned short* Ab = (unsigned short*)d_ws;
    unsigned short* Wt = (unsigned short*)((char*)d_ws + needA);
    conv_a<<<2048, 256, 0, stream>>>(A, Ab, (M_ * K_) / 8);
    dim3 gw(N_ / 64, K_ / 64, E_);
    conv_wT<<<gw, 256, 0, stream>>>(W, Wt, 0);
    dim3 gg(N_ / BN, M_ / BM + E_);
    moe_gemm_bf16<<<gg, 256, 0, stream>>>(Ab, Wt, gs, bias, C, -1, (size_t)N_ * K_);
  } else if (ws_size >= needA + needW1) {
    unsigned short* Ab = (unsigned short*)d_ws;
    unsigned short* Wt = (unsigned short*)((char*)d_ws + needA);
    conv_a<<<2048, 256, 0, stream>>>(A, Ab, (M_ * K_) / 8);
    for (int e = 0; e < E_; ++e) {
      dim3 gw(N_ / 64, K_ / 64, 1);
      conv_wT<<<gw, 256, 0, stream>>>(W, Wt, e);
      dim3 gg(N_ / BN, M_ / BM);
      moe_gemm_bf16<<<gg, 256, 0, stream>>>(Ab, Wt, gs, bias, C, e, 0);
    }
  } else {
    dim3 gn(N_ / 16, M_ / 16);
    moe_naive<<<gn, 256, 0, stream>>>(A, W, gs, bias, C);
  }
}

// Round 2
// 483.143 us; speedup vs baseline: 1.1365x; 1.1365x over previous
//
#include <hip/hip_runtime.h>
#include <stdint.h>

#define E_ 8
#define M_ 8192
#define K_ 2048
#define N_ 8192

#define BM 128
#define BN 256
#define BK 64
#define NT (K_ / BK)                      // 32
#define TILE_A_BYTES (BM * BK * 2)        // 16384
#define TILE_B_BYTES (BN * BK * 2)        // 32768
#define TILE_BYTES (TILE_A_BYTES + TILE_B_BYTES)  // 49152
#define LDS_BYTES (3 * TILE_BYTES)        // 147456

typedef __attribute__((ext_vector_type(8))) short bf16x8;
typedef __attribute__((ext_vector_type(4))) float f32x4;
typedef __attribute__((ext_vector_type(8))) unsigned short us8;

__device__ __forceinline__ unsigned short f2bf(float f) {
  union { float f; uint32_t u; } v; v.f = f;
  uint32_t u = v.u;
  uint32_t r = (u + 0x7FFFu + ((u >> 16) & 1u)) >> 16;
  return (unsigned short)r;
}

__device__ __forceinline__ void gload_lds16(const void* g, void* l) {
  __builtin_amdgcn_global_load_lds(
      (const __attribute__((address_space(1))) unsigned int*)g,
      (__attribute__((address_space(3))) unsigned int*)l,
      16, 0, 0);
}

// ---------------- fp32 -> bf16, layout preserving (inputs) ----------------
__global__ __launch_bounds__(256) void conv_a(const float* __restrict__ A,
                                              unsigned short* __restrict__ Ab,
                                              int n8) {
  int stride = gridDim.x * blockDim.x;
  for (int idx = blockIdx.x * blockDim.x + threadIdx.x; idx < n8; idx += stride) {
    const float4* p = reinterpret_cast<const float4*>(A) + (size_t)idx * 2;
    float4 x0 = p[0], x1 = p[1];
    us8 o;
    o[0] = f2bf(x0.x); o[1] = f2bf(x0.y); o[2] = f2bf(x0.z); o[3] = f2bf(x0.w);
    o[4] = f2bf(x1.x); o[5] = f2bf(x1.y); o[6] = f2bf(x1.z); o[7] = f2bf(x1.w);
    *reinterpret_cast<us8*>(Ab + (size_t)idx * 8) = o;
  }
}

// ------------- fp32 W[e][K][N] -> bf16 Wt[e][N][K] (transpose) -------------
__global__ __launch_bounds__(256) void conv_wT(const float* __restrict__ W,
                                               unsigned short* __restrict__ Wt,
                                               int e_fixed) {
  __shared__ float t[64][65];
  int tid = threadIdx.x;
  int tx = tid & 63, ty = tid >> 6;
  int n0 = blockIdx.x * 64, k0 = blockIdx.y * 64;
  int e = (gridDim.z > 1) ? blockIdx.z : e_fixed;
  size_t win = (size_t)e * K_ * N_;
  size_t wout = (gridDim.z > 1) ? ((size_t)e * K_ * N_) : 0;

  #pragma unroll
  for (int r = 0; r < 16; ++r) {
    int kl = r * 4 + ty;
    t[kl][tx] = W[win + (size_t)(k0 + kl) * N_ + n0 + tx];
  }
  __syncthreads();
  // 4B packed writes: lane covers k-pair px of row nl
  int px = tid & 31, py = tid >> 5;  // px: k-pair 0..31, py: 0..7
  #pragma unroll
  for (int r = 0; r < 8; ++r) {
    int nl = r * 8 + py;
    unsigned int pack = (unsigned int)f2bf(t[2 * px][nl]) |
                        ((unsigned int)f2bf(t[2 * px + 1][nl]) << 16);
    *reinterpret_cast<unsigned int*>(Wt + wout + (size_t)(n0 + nl) * K_ + k0 + 2 * px) = pack;
  }
}

// ------------- grouped bf16 GEMM: 128x256 tile, BK=64, ring-3 LDS -------------
// T2 swizzle: phys_byte = logical_byte ^ (((logical>>7)&7)<<4)  (128B rows)
// T4 counted vmcnt(6): ring-3 buffers, stage t+2 while computing t.
__global__ __launch_bounds__(512, 2) void moe_gemm_bf16(
    const unsigned short* __restrict__ Ab,   // [M][K] bf16
    const unsigned short* __restrict__ Wt,   // [e][N][K] bf16
    const int* __restrict__ gs,
    const float* __restrict__ bias,
    float* __restrict__ C,
    int only_expert, size_t wt_stride) {
  extern __shared__ char smem[];

  int tile_n = blockIdx.x;
  int tile_m = blockIdx.y;

  // map row-tile -> (expert, row_start, rows); wave-uniform scalar scan
  int expert = -1, row_start = 0, rows = 0;
  if (only_expert >= 0) {
    int off = 0;
    for (int e = 0; e < only_expert; ++e) off += gs[e];
    int g = gs[only_expert];
    int t0 = tile_m * BM;
    if (t0 >= g) return;
    expert = only_expert;
    row_start = off + t0;
    rows = min(BM, g - t0);
  } else {
    int acc = 0, off = 0;
    for (int e = 0; e < E_; ++e) {
      int g = gs[e];
      int t = (g + BM - 1) / BM;
      if (expert < 0 && tile_m < acc + t) {
        int lt = tile_m - acc;
        expert = e;
        row_start = off + lt * BM;
        rows = min(BM, g - lt * BM);
      }
      acc += t;
      off += g;
    }
    if (expert < 0) return;
  }

  const unsigned short* WtE = Wt + (size_t)expert * wt_stride;

  int tid = threadIdx.x;
  int lane = tid & 63;
  int wave = tid >> 6;       // 0..7
  int wr = wave >> 2;        // 0..1 (M)
  int wc = wave & 3;         // 0..3 (N)
  int n0 = tile_n * BN;

  // ---- staging precompute (per-thread, tile-invariant) ----
  // A: 2 chunks of 1KB per wave; B: 4 chunks.
  const unsigned short* asrc[2];
  int adst[2];
  #pragma unroll
  for (int i = 0; i < 2; ++i) {
    int off = wave * 2048 + i * 1024 + lane * 16;        // linear dest byte in A region
    int l = off ^ (((off >> 7) & 7) << 4);               // logical byte (inverse swz)
    int arow = l >> 7;                                   // 0..127
    int acol = (l & 127) >> 1;                           // bf16 elem 0..63
    int ar = arow < rows ? arow : 0;                     // clamp partial tiles
    asrc[i] = Ab + (size_t)(row_start + ar) * K_ + acol;
    adst[i] = off;
  }
  const unsigned short* bsrc[4];
  int bdst[4];
  #pragma unroll
  for (int i = 0; i < 4; ++i) {
    int off = wave * 4096 + i * 1024 + lane * 16;        // linear dest byte in B region
    int l = off ^ (((off >> 7) & 7) << 4);
    int brow = l >> 7;                                   // 0..255
    int bcol = (l & 127) >> 1;
    bsrc[i] = WtE + (size_t)(n0 + brow) * K_ + bcol;
    bdst[i] = TILE_A_BYTES + off;
  }

#define STAGE(bufbase, kt)                                        \
  do {                                                            \
    int kko_ = (kt) * BK;                                         \
    _Pragma("unroll")                                             \
    for (int i_ = 0; i_ < 2; ++i_)                                \
      gload_lds16(asrc[i_] + kko_, (bufbase) + adst[i_]);         \
    _Pragma("unroll")                                             \
    for (int i_ = 0; i_ < 4; ++i_)                                \
      gload_lds16(bsrc[i_] + kko_, (bufbase) + bdst[i_]);         \
  } while (0)

  // ---- fragment read offsets (swizzled) ----
  int xm = (lane & 7) << 4;              // per-thread XOR mask (row&7 == lane&7)
  int colrd = (lane >> 4) * 16;          // 16B chunk within 128B row
  int arow_rd = wr * 64 + (lane & 15);
  int brow_rd = wc * 64 + (lane & 15);

  f32x4 acc4[4][4];
  #pragma unroll
  for (int i = 0; i < 4; ++i)
    #pragma unroll
    for (int j = 0; j < 4; ++j)
      acc4[i][j] = f32x4{0.f, 0.f, 0.f, 0.f};

  char* b0 = smem;
  char* b1 = smem + TILE_BYTES;
  char* b2 = smem + 2 * TILE_BYTES;

  STAGE(b0, 0);
  STAGE(b1, 1);

  int cur = 0;
  for (int t = 0; t < NT; ++t) {
    if (t + 2 < NT) {
      asm volatile("s_waitcnt vmcnt(6)" ::: "memory");
    } else {
      asm volatile("s_waitcnt vmcnt(0)" ::: "memory");
    }
    __builtin_amdgcn_s_barrier();

    char* cb = smem + cur * TILE_BYTES;
    int nxt2 = cur + 2; if (nxt2 >= 3) nxt2 -= 3;
    if (t + 2 < NT) {
      char* nb = smem + nxt2 * TILE_BYTES;
      STAGE(nb, t + 2);
    }

    const char* la = cb;
    const char* lb = cb + TILE_A_BYTES;

    bf16x8 af[4][2];
    #pragma unroll
    for (int mi = 0; mi < 4; ++mi)
      #pragma unroll
      for (int ks = 0; ks < 2; ++ks) {
        int loff = (arow_rd + mi * 16) * 128 + ks * 64 + colrd;
        af[mi][ks] = *reinterpret_cast<const bf16x8*>(la + (loff ^ xm));
      }

    // phase 0: N-half 0
    {
      bf16x8 bfr[2][2];
      #pragma unroll
      for (int nj = 0; nj < 2; ++nj)
        #pragma unroll
        for (int ks = 0; ks < 2; ++ks) {
          int loff = (brow_rd + nj * 16) * 128 + ks * 64 + colrd;
          bfr[nj][ks] = *reinterpret_cast<const bf16x8*>(lb + (loff ^ xm));
        }
      __builtin_amdgcn_s_setprio(1);
      #pragma unroll
      for (int mi = 0; mi < 4; ++mi)
        #pragma unroll
        for (int nj = 0; nj < 2; ++nj)
          #pragma unroll
          for (int ks = 0; ks < 2; ++ks)
            acc4[mi][nj] = __builtin_amdgcn_mfma_f32_16x16x32_bf16(
                af[mi][ks], bfr[nj][ks], acc4[mi][nj], 0, 0, 0);
      __builtin_amdgcn_s_setprio(0);
    }
    // phase 1: N-half 1
    {
      bf16x8 bfr[2][2];
      #pragma unroll
      for (int nj = 0; nj < 2; ++nj)
        #pragma unroll
        for (int ks = 0; ks < 2; ++ks) {
          int loff = (brow_rd + (nj + 2) * 16) * 128 + ks * 64 + colrd;
          bfr[nj][ks] = *reinterpret_cast<const bf16x8*>(lb + (loff ^ xm));
        }
      __builtin_amdgcn_s_setprio(1);
      #pragma unroll
      for (int mi = 0; mi < 4; ++mi)
        #pragma unroll
        for (int nj = 0; nj < 2; ++nj)
          #pragma unroll
          for (int ks = 0; ks < 2; ++ks)
            acc4[mi][nj + 2] = __builtin_amdgcn_mfma_f32_16x16x32_bf16(
                af[mi][ks], bfr[nj][ks], acc4[mi][nj + 2], 0, 0, 0);
      __builtin_amdgcn_s_setprio(0);
    }

    cur = cur + 1 == 3 ? 0 : cur + 1;
  }
#undef STAGE

  // epilogue: C = acc + bias ; C/D layout col=lane&15, row=(lane>>4)*4+reg
  float bv[4];
  #pragma unroll
  for (int nj = 0; nj < 4; ++nj) bv[nj] = bias[n0 + wc * 64 + nj * 16 + (lane & 15)];
  #pragma unroll
  for (int mi = 0; mi < 4; ++mi) {
    int r0 = wr * 64 + mi * 16 + (lane >> 4) * 4;
    #pragma unroll
    for (int r = 0; r < 4; ++r) {
      int lr = r0 + r;
      if (lr < rows) {
        float* Cp = C + (size_t)(row_start + lr) * N_ + n0 + wc * 64 + (lane & 15);
        #pragma unroll
        for (int nj = 0; nj < 4; ++nj) Cp[nj * 16] = acc4[mi][nj][r] + bv[nj];
      }
    }
  }
}

// ---------------- naive fp32 fallback (only if workspace too small) ----------------
__global__ __launch_bounds__(256) void moe_naive(const float* __restrict__ A,
                                                 const float* __restrict__ W,
                                                 const int* __restrict__ gs,
                                                 const float* __restrict__ bias,
                                                 float* __restrict__ C) {
  int col = blockIdx.x * 16 + (threadIdx.x & 15);
  int row = blockIdx.y * 16 + (threadIdx.x >> 4);
  int acc = 0, e = E_ - 1;
  for (int i = 0; i < E_; ++i) {
    int g = gs[i];
    if (row >= acc && row < acc + g) { e = i; break; }
    acc += g;
  }
  const float* a = A + (size_t)row * K_;
  const float* w = W + (size_t)e * K_ * N_ + col;
  float s = 0.f;
  for (int k = 0; k < K_; ++k) s += a[k] * w[(size_t)k * N_];
  C[(size_t)row * N_ + col] = s + bias[col];
}

extern "C" void kernel_launch(void* const* d_in, const int* in_sizes, int n_in,
                              void* d_out, int out_size, void* d_ws, size_t ws_size,
                              hipStream_t stream) {
  const float* A = (const float*)d_in[0];
  const float* W = (const float*)d_in[1];
  const int* gs = (const int*)d_in[2];
  const float* bias = (const float*)d_in[3];
  float* C = (float*)d_out;

  const size_t needA = (size_t)M_ * K_ * 2;          // 32 MiB
  const size_t needWall = (size_t)E_ * K_ * N_ * 2;  // 256 MiB
  const size_t needW1 = (size_t)K_ * N_ * 2;         // 32 MiB

  (void)hipFuncSetAttribute((const void*)moe_gemm_bf16,
                            hipFuncAttributeMaxDynamicSharedMemorySize, LDS_BYTES);

  if (ws_size >= needA + needWall) {
    unsigned short* Abf = (unsigned short*)d_ws;
    unsigned short* Wtb = (unsigned short*)((char*)d_ws + needA);
    conv_a<<<2048, 256, 0, stream>>>(A, Abf, (M_ * K_) / 8);
    dim3 gw(N_ / 64, K_ / 64, E_);
    conv_wT<<<gw, 256, 0, stream>>>(W, Wtb, 0);
    dim3 gg(N_ / BN, M_ / BM + E_);
    moe_gemm_bf16<<<gg, 512, LDS_BYTES, stream>>>(Abf, Wtb, gs, bias, C, -1, (size_t)N_ * K_);
  } else if (ws_size >= needA + needW1) {
    unsigned short* Abf = (unsigned short*)d_ws;
    unsigned short* Wtb = (unsigned short*)((char*)d_ws + needA);
    conv_a<<<2048, 256, 0, stream>>>(A, Abf, (M_ * K_) / 8);
    for (int e = 0; e < E_; ++e) {
      dim3 gw(N_ / 64, K_ / 64, 1);
      conv_wT<<<gw, 256, 0, stream>>>(W, Wtb, e);
      dim3 gg(N_ / BN, M_ / BM);
      moe_gemm_bf16<<<gg, 512, LDS_BYTES, stream>>>(Abf, Wtb, gs, bias, C, e, 0);
    }
  } else {
    dim3 gn(N_ / 16, M_ / 16);
    moe_naive<<<gn, 256, 0, stream>>>(A, W, gs, bias, C);
  }
}

// Round 3
// 444.157 us; speedup vs baseline: 1.2363x; 1.0878x over previous
//
#include <hip/hip_runtime.h>
#include <stdint.h>

#define E_ 8
#define M_ 8192
#define K_ 2048
#define N_ 8192

#define BM 256
#define BN 256
#define BK 64
#define NT (K_ / BK)        // 32 K-tiles
#define LDS_BYTES 131072    // 2 dbuf x 64KB

typedef __attribute__((ext_vector_type(8))) short bf16x8;
typedef __attribute__((ext_vector_type(4))) float f32x4;
typedef __attribute__((ext_vector_type(8))) unsigned short us8;

__device__ __forceinline__ unsigned short f2bf(float f) {
  union { float f; uint32_t u; } v; v.f = f;
  uint32_t u = v.u;
  uint32_t r = (u + 0x7FFFu + ((u >> 16) & 1u)) >> 16;
  return (unsigned short)r;
}

__device__ __forceinline__ void gload_lds16(const void* g, void* l) {
  __builtin_amdgcn_global_load_lds(
      (const __attribute__((address_space(1))) unsigned int*)g,
      (__attribute__((address_space(3))) unsigned int*)l,
      16, 0, 0);
}

// ---------------- fp32 -> bf16, layout preserving (inputs) ----------------
__global__ __launch_bounds__(256) void conv_a(const float* __restrict__ A,
                                              unsigned short* __restrict__ Ab,
                                              int n8) {
  int stride = gridDim.x * blockDim.x;
  for (int idx = blockIdx.x * blockDim.x + threadIdx.x; idx < n8; idx += stride) {
    const float4* p = reinterpret_cast<const float4*>(A) + (size_t)idx * 2;
    float4 x0 = p[0], x1 = p[1];
    us8 o;
    o[0] = f2bf(x0.x); o[1] = f2bf(x0.y); o[2] = f2bf(x0.z); o[3] = f2bf(x0.w);
    o[4] = f2bf(x1.x); o[5] = f2bf(x1.y); o[6] = f2bf(x1.z); o[7] = f2bf(x1.w);
    *reinterpret_cast<us8*>(Ab + (size_t)idx * 8) = o;
  }
}

// ------------- fp32 W[e][K][N] -> bf16 Wt[e][N][K] (transpose) -------------
__global__ __launch_bounds__(256) void conv_wT(const float* __restrict__ W,
                                               unsigned short* __restrict__ Wt,
                                               int e_fixed) {
  __shared__ float t[64][65];
  int tid = threadIdx.x;
  int tx = tid & 63, ty = tid >> 6;
  int n0 = blockIdx.x * 64, k0 = blockIdx.y * 64;
  int e = (gridDim.z > 1) ? blockIdx.z : e_fixed;
  size_t win = (size_t)e * K_ * N_;
  size_t wout = (gridDim.z > 1) ? win : 0;

  #pragma unroll
  for (int r = 0; r < 16; ++r) {
    int kl = r * 4 + ty;
    t[kl][tx] = W[win + (size_t)(k0 + kl) * N_ + n0 + tx];
  }
  __syncthreads();
  int px = tid & 31, py = tid >> 5;
  #pragma unroll
  for (int r = 0; r < 8; ++r) {
    int nl = r * 8 + py;
    unsigned int pack = (unsigned int)f2bf(t[2 * px][nl]) |
                        ((unsigned int)f2bf(t[2 * px + 1][nl]) << 16);
    *reinterpret_cast<unsigned int*>(Wt + wout + (size_t)(n0 + nl) * K_ + k0 + 2 * px) = pack;
  }
}

// ------------- grouped bf16 GEMM: 256x256, BK=64, dbuf-2, 8-phase -------------
// LDS dbuf d at d*65536: A-h0 @0, A-h1 @16K, B-h0 @32K, B-h1 @48K.
// Half (16KB) is ks-major: ks*8192 + row*64 + slot*16, slot = kc ^ swz(row),
// swz(r) = (r&3)^((r>>2)&3).  Stage granularity = one 8KB (X,h,ks) chunk.
__global__ __launch_bounds__(512, 2) void moe_gemm_bf16(
    const unsigned short* __restrict__ Ab,   // [M][K] bf16
    const unsigned short* __restrict__ Wt,   // [e][N][K] bf16
    const int* __restrict__ gs,
    const float* __restrict__ bias,
    float* __restrict__ C,
    int only_expert, size_t wt_stride) {
  extern __shared__ char smem[];

  int tile_n = blockIdx.x;
  int tile_m = blockIdx.y;

  int expert = -1, row_start = 0, rows = 0;
  if (only_expert >= 0) {
    int off = 0;
    for (int e = 0; e < only_expert; ++e) off += gs[e];
    int g = gs[only_expert];
    int t0 = tile_m * BM;
    if (t0 >= g) return;
    expert = only_expert;
    row_start = off + t0;
    rows = min(BM, g - t0);
  } else {
    int acc = 0, off = 0;
    for (int e = 0; e < E_; ++e) {
      int g = gs[e];
      int t = (g + BM - 1) / BM;
      if (expert < 0 && tile_m < acc + t) {
        int lt = tile_m - acc;
        expert = e;
        row_start = off + lt * BM;
        rows = min(BM, g - lt * BM);
      }
      acc += t;
      off += g;
    }
    if (expert < 0) return;
  }

  const unsigned short* WtE = Wt + (size_t)expert * wt_stride;

  int tid = threadIdx.x;          // 0..511
  int lane = tid & 63;
  int wave = tid >> 6;            // 0..7
  int wr = wave >> 2;             // 0..1 (M half)
  int wc = wave & 3;              // 0..3 (N quarter)
  int bh = wc >> 1;               // B half
  int ln15 = lane & 15;
  int n0 = tile_n * BN;

  // ---- fragment read bases (swizzled; swz(row) independent of mi/nj) ----
  int sl16 = (((lane >> 4) ^ ((ln15 & 3) ^ ((ln15 >> 2) & 3))) << 4);
  int aRB = wr * 16384 + ln15 * 64 + sl16;                          // +mi*1024 +ks*8192
  int bRB = 32768 + bh * 16384 + ((wc & 1) * 64 + ln15) * 64 + sl16; // +nj*1024 +ks*8192

  // ---- staging precompute: thread stages 16B of each 8KB (X,h,ks) chunk ----
  int soff = tid * 16;            // dest offset within chunk
  int srow = soff >> 6;           // 0..127
  int sslot = (soff >> 4) & 3;
  int skc = sslot ^ ((srow & 3) ^ ((srow >> 2) & 3));
  int scol0 = skc * 8;            // element col within 64-elem row: +ks*32 (+kt*64)

  const unsigned short* aS[2][2];  // [h][ks]
  const unsigned short* bS[2][2];
  #pragma unroll
  for (int h = 0; h < 2; ++h) {
    int r = h * 128 + srow;
    int gr = r < rows ? r : 0;     // clamp partial M tiles
    #pragma unroll
    for (int ks = 0; ks < 2; ++ks) {
      aS[h][ks] = Ab + (size_t)(row_start + gr) * K_ + ks * 32 + scol0;
      bS[h][ks] = WtE + (size_t)(n0 + h * 128 + srow) * K_ + ks * 32 + scol0;
    }
  }

#define STG_A(DB, h, ks, kt) \
  gload_lds16(aS[h][ks] + (kt) * 64, smem + (DB) + (h) * 16384 + (ks) * 8192 + soff)
#define STG_B(DB, h, ks, kt) \
  gload_lds16(bS[h][ks] + (kt) * 64, smem + (DB) + 32768 + (h) * 16384 + (ks) * 8192 + soff)

  f32x4 acc4[8][4];
  #pragma unroll
  for (int i = 0; i < 8; ++i)
    #pragma unroll
    for (int j = 0; j < 4; ++j)
      acc4[i][j] = f32x4{0.f, 0.f, 0.f, 0.f};

  // prologue: stage tile 0 into dbuf0, canonical order [Ak0, Bk0, Ak1, Bk1]
  STG_A(0, 0, 0, 0); STG_A(0, 1, 0, 0);
  STG_B(0, 0, 0, 0); STG_B(0, 1, 0, 0);
  STG_A(0, 0, 1, 0); STG_A(0, 1, 1, 0);
  STG_B(0, 0, 1, 0); STG_B(0, 1, 1, 0);

  // Per K-tile: 4 phases (ks x m-half), 16 MFMA each.
  // vmcnt(4) before P0 (ks0 chunks in) and P2 (ks1 chunks in) - never 0.
#define ITER(T, DB, DBN)                                                      \
  do {                                                                        \
    int ktn = (T) + 1; if (ktn >= NT) ktn = 0;                                \
    asm volatile("s_waitcnt vmcnt(4)" ::: "memory");                          \
    __builtin_amdgcn_s_barrier();                                             \
    bf16x8 a0[4], b0[4], a1[4];                                               \
    _Pragma("unroll") for (int mi = 0; mi < 4; ++mi)                          \
      a0[mi] = *(const bf16x8*)(smem + (DB) + aRB + mi * 1024);               \
    _Pragma("unroll") for (int nj = 0; nj < 4; ++nj)                          \
      b0[nj] = *(const bf16x8*)(smem + (DB) + bRB + nj * 1024);               \
    STG_A(DBN, 0, 0, ktn); STG_A(DBN, 1, 0, ktn);                             \
    asm volatile("s_waitcnt lgkmcnt(0)" ::: "memory");                        \
    __builtin_amdgcn_sched_barrier(0);                                        \
    __builtin_amdgcn_s_setprio(1);                                            \
    _Pragma("unroll") for (int mi = 0; mi < 4; ++mi)                          \
      _Pragma("unroll") for (int nj = 0; nj < 4; ++nj)                        \
        acc4[mi][nj] = __builtin_amdgcn_mfma_f32_16x16x32_bf16(               \
            a0[mi], b0[nj], acc4[mi][nj], 0, 0, 0);                           \
    __builtin_amdgcn_s_setprio(0);                                            \
    _Pragma("unroll") for (int mi = 0; mi < 4; ++mi)                          \
      a1[mi] = *(const bf16x8*)(smem + (DB) + aRB + (mi + 4) * 1024);         \
    STG_B(DBN, 0, 0, ktn); STG_B(DBN, 1, 0, ktn);                             \
    asm volatile("s_waitcnt lgkmcnt(0)" ::: "memory");                        \
    __builtin_amdgcn_sched_barrier(0);                                        \
    __builtin_amdgcn_s_setprio(1);                                            \
    _Pragma("unroll") for (int mi = 0; mi < 4; ++mi)                          \
      _Pragma("unroll") for (int nj = 0; nj < 4; ++nj)                        \
        acc4[mi + 4][nj] = __builtin_amdgcn_mfma_f32_16x16x32_bf16(           \
            a1[mi], b0[nj], acc4[mi + 4][nj], 0, 0, 0);                       \
    __builtin_amdgcn_s_setprio(0);                                            \
    asm volatile("s_waitcnt vmcnt(4)" ::: "memory");                          \
    __builtin_amdgcn_s_barrier();                                             \
    _Pragma("unroll") for (int mi = 0; mi < 4; ++mi)                          \
      a0[mi] = *(const bf16x8*)(smem + (DB) + aRB + 8192 + mi * 1024);        \
    _Pragma("unroll") for (int nj = 0; nj < 4; ++nj)                          \
      b0[nj] = *(const bf16x8*)(smem + (DB) + bRB + 8192 + nj * 1024);        \
    STG_A(DBN, 0, 1, ktn); STG_A(DBN, 1, 1, ktn);                             \
    asm volatile("s_waitcnt lgkmcnt(0)" ::: "memory");                        \
    __builtin_amdgcn_sched_barrier(0);                                        \
    __builtin_amdgcn_s_setprio(1);                                            \
    _Pragma("unroll") for (int mi = 0; mi < 4; ++mi)                          \
      _Pragma("unroll") for (int nj = 0; nj < 4; ++nj)                        \
        acc4[mi][nj] = __builtin_amdgcn_mfma_f32_16x16x32_bf16(               \
            a0[mi], b0[nj], acc4[mi][nj], 0, 0, 0);                           \
    __builtin_amdgcn_s_setprio(0);                                            \
    _Pragma("unroll") for (int mi = 0; mi < 4; ++mi)                          \
      a1[mi] = *(const bf16x8*)(smem + (DB) + aRB + 8192 + (mi + 4) * 1024);  \
    STG_B(DBN, 0, 1, ktn); STG_B(DBN, 1, 1, ktn);                             \
    asm volatile("s_waitcnt lgkmcnt(0)" ::: "memory");                        \
    __builtin_amdgcn_sched_barrier(0);                                        \
    __builtin_amdgcn_s_setprio(1);                                            \
    _Pragma("unroll") for (int mi = 0; mi < 4; ++mi)                          \
      _Pragma("unroll") for (int nj = 0; nj < 4; ++nj)                        \
        acc4[mi + 4][nj] = __builtin_amdgcn_mfma_f32_16x16x32_bf16(           \
            a1[mi], b0[nj], acc4[mi + 4][nj], 0, 0, 0);                       \
    __builtin_amdgcn_s_setprio(0);                                            \
  } while (0)

  for (int t2 = 0; t2 < NT; t2 += 2) {
    ITER(t2, 0, 65536);
    ITER(t2 + 1, 65536, 0);
  }
#undef ITER
#undef STG_A
#undef STG_B

  asm volatile("s_waitcnt vmcnt(0)" ::: "memory");  // drain wrapped tail stages

  // epilogue: C = acc + bias ; C/D layout col=lane&15, row=(lane>>4)*4+reg
  float bv[4];
  #pragma unroll
  for (int nj = 0; nj < 4; ++nj) bv[nj] = bias[n0 + wc * 64 + nj * 16 + ln15];
  #pragma unroll
  for (int mi = 0; mi < 8; ++mi) {
    int r0 = wr * 128 + mi * 16 + (lane >> 4) * 4;
    #pragma unroll
    for (int r = 0; r < 4; ++r) {
      int lr = r0 + r;
      if (lr < rows) {
        float* Cp = C + (size_t)(row_start + lr) * N_ + n0 + wc * 64 + ln15;
        #pragma unroll
        for (int nj = 0; nj < 4; ++nj) Cp[nj * 16] = acc4[mi][nj][r] + bv[nj];
      }
    }
  }
}

// ---------------- naive fp32 fallback (only if workspace too small) ----------------
__global__ __launch_bounds__(256) void moe_naive(const float* __restrict__ A,
                                                 const float* __restrict__ W,
                                                 const int* __restrict__ gs,
                                                 const float* __restrict__ bias,
                                                 float* __restrict__ C) {
  int col = blockIdx.x * 16 + (threadIdx.x & 15);
  int row = blockIdx.y * 16 + (threadIdx.x >> 4);
  int acc = 0, e = E_ - 1;
  for (int i = 0; i < E_; ++i) {
    int g = gs[i];
    if (row >= acc && row < acc + g) { e = i; break; }
    acc += g;
  }
  const float* a = A + (size_t)row * K_;
  const float* w = W + (size_t)e * K_ * N_ + col;
  float s = 0.f;
  for (int k = 0; k < K_; ++k) s += a[k] * w[(size_t)k * N_];
  C[(size_t)row * N_ + col] = s + bias[col];
}

extern "C" void kernel_launch(void* const* d_in, const int* in_sizes, int n_in,
                              void* d_out, int out_size, void* d_ws, size_t ws_size,
                              hipStream_t stream) {
  const float* A = (const float*)d_in[0];
  const float* W = (const float*)d_in[1];
  const int* gs = (const int*)d_in[2];
  const float* bias = (const float*)d_in[3];
  float* C = (float*)d_out;

  const size_t needA = (size_t)M_ * K_ * 2;          // 32 MiB
  const size_t needWall = (size_t)E_ * K_ * N_ * 2;  // 256 MiB
  const size_t needW1 = (size_t)K_ * N_ * 2;         // 32 MiB

  (void)hipFuncSetAttribute((const void*)moe_gemm_bf16,
                            hipFuncAttributeMaxDynamicSharedMemorySize, LDS_BYTES);

  if (ws_size >= needA + needWall) {
    unsigned short* Abf = (unsigned short*)d_ws;
    unsigned short* Wtb = (unsigned short*)((char*)d_ws + needA);
    conv_a<<<2048, 256, 0, stream>>>(A, Abf, (M_ * K_) / 8);
    dim3 gw(N_ / 64, K_ / 64, E_);
    conv_wT<<<gw, 256, 0, stream>>>(W, Wtb, 0);
    dim3 gg(N_ / BN, M_ / BM + E_);
    moe_gemm_bf16<<<gg, 512, LDS_BYTES, stream>>>(Abf, Wtb, gs, bias, C, -1, (size_t)N_ * K_);
  } else if (ws_size >= needA + needW1) {
    unsigned short* Abf = (unsigned short*)d_ws;
    unsigned short* Wtb = (unsigned short*)((char*)d_ws + needA);
    conv_a<<<2048, 256, 0, stream>>>(A, Abf, (M_ * K_) / 8);
    for (int e = 0; e < E_; ++e) {
      dim3 gw(N_ / 64, K_ / 64, 1);
      conv_wT<<<gw, 256, 0, stream>>>(W, Wtb, e);
      dim3 gg(N_ / BN, M_ / BM);
      moe_gemm_bf16<<<gg, 512, LDS_BYTES, stream>>>(Abf, Wtb, gs, bias, C, e, 0);
    }
  } else {
    dim3 gn(N_ / 16, M_ / 16);
    moe_naive<<<gn, 256, 0, stream>>>(A, W, gs, bias, C);
  }
}